// Round 2
// baseline (1137.748 us; speedup 1.0000x reference)
//
#include <hip/hip_runtime.h>

typedef unsigned short u16;
typedef unsigned int u32;

#define BN 16
#define CHN 64
#define HH 192
#define WW 192
#define HWSZ (HH*WW)          // 36864
#define KDY 4
#define HIDN 17
#define NG 8
#define TEMP_ 30.0f
#define EPSV 1e-5f
#define NSLOPE 0.01f
#define FSZ (CHN*CHN*9)       // 36864 filter elems per sample

__device__ __forceinline__ float bf2f(u32 v) {
    u32 u = v << 16; float f; __builtin_memcpy(&f, &u, 4); return f;
}
__device__ __forceinline__ u16 f2bf(float f) {
    u32 u; __builtin_memcpy(&u, &f, 4);
    u32 r = (u + 0x7fffu + ((u >> 16) & 1u)) >> 16;   // round-nearest-even
    return (u16)r;
}
// dtype-agnostic scalar load: idx in ELEMENTS of the logical tensor
__device__ __forceinline__ float ldE(const void* p, int idx, int fp32) {
    return fp32 ? ((const float*)p)[idx] : bf2f(((const u16*)p)[idx]);
}

// ---------------- Stage 0: dtype detection ----------------
// Interpret first 16384 u16 of x as bf16. True bf16 N(0,1) data never exceeds
// |v|>1e4; fp32 bits read as bf16 halves produce huge/NaN values w.p. ~0.44
// per low half. flag: 1 = fp32 tensors, 0 = bf16 tensors.
__global__ void detect_kernel(const u16* __restrict__ xr, int* __restrict__ flag) {
    __shared__ int c;
    if (threadIdx.x == 0) c = 0;
    __syncthreads();
    int bad = 0;
    for (int i = threadIdx.x; i < 16384; i += 256) {
        float v = bf2f(xr[i]);
        if (!(fabsf(v) <= 1e4f)) bad = 1;   // catches NaN too
    }
    if (bad) atomicAdd(&c, 1);
    __syncthreads();
    if (threadIdx.x == 0) *flag = (c > 0) ? 1 : 0;
}

// ---------------- Stage 1: global average pool ----------------
__global__ void pool_kernel(const void* __restrict__ x, float* __restrict__ pooled,
                            const int* __restrict__ flag) {
    const int fp32 = *flag;
    int bc = blockIdx.x;
    float s = 0.f;
    if (fp32) {
        const float4* pv = (const float4*)((const float*)x + (size_t)bc * HWSZ);
        for (int i = threadIdx.x; i < HWSZ / 4; i += 256) {
            float4 v = pv[i];
            s += v.x + v.y + v.z + v.w;
        }
    } else {
        const uint4* pv = (const uint4*)((const u16*)x + (size_t)bc * HWSZ);
        for (int i = threadIdx.x; i < HWSZ / 8; i += 256) {
            uint4 v = pv[i];
            s += bf2f(v.x & 0xffff) + bf2f(v.x >> 16)
               + bf2f(v.y & 0xffff) + bf2f(v.y >> 16)
               + bf2f(v.z & 0xffff) + bf2f(v.z >> 16)
               + bf2f(v.w & 0xffff) + bf2f(v.w >> 16);
        }
    }
    #pragma unroll
    for (int off = 32; off > 0; off >>= 1) s += __shfl_down(s, off);
    __shared__ float ls[4];
    if ((threadIdx.x & 63) == 0) ls[threadIdx.x >> 6] = s;
    __syncthreads();
    if (threadIdx.x == 0)
        pooled[bc] = (ls[0] + ls[1] + ls[2] + ls[3]) * (1.0f / HWSZ);
}

// ---------------- Stage 2: attention MLP + softmax (also zeroes stats) ------
__global__ void attn_kernel(const float* __restrict__ pooled,
                            const void* __restrict__ w1, const void* __restrict__ w2,
                            const void* __restrict__ b2, float* __restrict__ attn,
                            float* __restrict__ stats, const int* __restrict__ flag) {
    const int fp32 = *flag;
    int t = threadIdx.x;
    for (int i = t; i < BN * NG * 2; i += 64) stats[i] = 0.f;  // zero GN stats
    if (t < BN) {
        const float* pr = pooled + t * CHN;
        float hb[HIDN];
        #pragma unroll
        for (int h = 0; h < HIDN; h++) {
            float s = 0.f;
            for (int c = 0; c < CHN; c++) s += ldE(w1, h * CHN + c, fp32) * pr[c];
            hb[h] = fmaxf(s, 0.f);
        }
        float scv[KDY]; float m = -3e38f;
        #pragma unroll
        for (int k = 0; k < KDY; k++) {
            float s = ldE(b2, k, fp32);
            for (int h = 0; h < HIDN; h++) s += ldE(w2, k * HIDN + h, fp32) * hb[h];
            s *= (1.0f / TEMP_);
            scv[k] = s; m = fmaxf(m, s);
        }
        float den = 0.f;
        #pragma unroll
        for (int k = 0; k < KDY; k++) { scv[k] = __expf(scv[k] - m); den += scv[k]; }
        float rd = 1.f / den;
        #pragma unroll
        for (int k = 0; k < KDY; k++) attn[t * KDY + k] = scv[k] * rd;
    }
}

// ---------------- Stage 3+4: per-sample conv (filters synthesized in staging)
// block = 256 threads: thread = (cog 0..15) x (pxg 0..15)
// thread computes co = cog*4..cog*4+3 for 8 pixels (row = pxg>>1, halfrow (pxg&1)*8)
// grid = (W/16, H/8, B)
#define CIC 8
__global__ void __launch_bounds__(256) conv_kernel(
        const void* __restrict__ x, const void* __restrict__ wts,
        const float* __restrict__ attn, void* __restrict__ y,
        float* __restrict__ stats, const int* __restrict__ flag) {
    __shared__ __align__(16) float xs[CIC * 10 * 20];    // padded rows (18->20)
    __shared__ __align__(16) float fs[CIC * CHN * 9];
    __shared__ float gsum[NG], gsq[NG];
    const int fp32 = *flag;
    const int b   = blockIdx.z;
    const int tr0 = blockIdx.y * 8;
    const int tc0 = blockIdx.x * 16;
    const int tid = threadIdx.x;
    const int cog = tid & 15;
    const int pxg = tid >> 4;
    const int r   = pxg >> 1;
    const int chf = (pxg & 1) * 8;
    const float a0 = attn[b * KDY + 0], a1 = attn[b * KDY + 1],
                a2 = attn[b * KDY + 2], a3 = attn[b * KDY + 3];
    float acc[4][8];
    #pragma unroll
    for (int j = 0; j < 4; j++)
        #pragma unroll
        for (int p = 0; p < 8; p++) acc[j][p] = 0.f;
    const size_t xbo = (size_t)b * CHN * HWSZ;

    for (int cib = 0; cib < CHN; cib += CIC) {
        __syncthreads();
        // stage x halo tile: CIC x 10 x 18
        for (int l = tid; l < CIC * 10 * 18; l += 256) {
            int ci = l / 180, rem = l % 180;
            int rr = rem / 18, cc = rem % 18;
            int gr = tr0 - 1 + rr, gc = tc0 - 1 + cc;
            float v = 0.f;
            if ((unsigned)gr < HH && (unsigned)gc < WW) {
                size_t off = xbo + (size_t)(cib + ci) * HWSZ + gr * WW + gc;
                v = fp32 ? ((const float*)x)[off] : bf2f(((const u16*)x)[off]);
            }
            xs[ci * 200 + rr * 20 + cc] = v;
        }
        // synthesize + stage filters: CIC x 64co x 9
        for (int l = tid; l < CIC * CHN * 9; l += 256) {
            int co = l / 72, rem = l % 72;
            int ci = rem / 9, tap = rem % 9;
            int widx = co * 576 + (cib + ci) * 9 + tap;
            float w0, w1v, w2v, w3v;
            if (fp32) {
                const float* wf = (const float*)wts;
                w0 = wf[widx]; w1v = wf[FSZ + widx];
                w2v = wf[2 * FSZ + widx]; w3v = wf[3 * FSZ + widx];
            } else {
                const u16* wh = (const u16*)wts;
                w0 = bf2f(wh[widx]); w1v = bf2f(wh[FSZ + widx]);
                w2v = bf2f(wh[2 * FSZ + widx]); w3v = bf2f(wh[3 * FSZ + widx]);
            }
            fs[ci * (CHN * 9) + co * 9 + tap] = a0 * w0 + a1 * w1v + a2 * w2v + a3 * w3v;
        }
        __syncthreads();
        for (int ci = 0; ci < CIC; ci++) {
            float xv[3][10];
            const float* xrow = xs + ci * 200 + r * 20 + chf;
            #pragma unroll
            for (int dr = 0; dr < 3; dr++) {
                const float* rp = xrow + dr * 20;
                float4 v0 = *(const float4*)rp;
                float4 v1 = *(const float4*)(rp + 4);
                xv[dr][0] = v0.x; xv[dr][1] = v0.y; xv[dr][2] = v0.z; xv[dr][3] = v0.w;
                xv[dr][4] = v1.x; xv[dr][5] = v1.y; xv[dr][6] = v1.z; xv[dr][7] = v1.w;
                xv[dr][8] = rp[8]; xv[dr][9] = rp[9];
            }
            const float* fr = fs + ci * (CHN * 9) + cog * 36;
            #pragma unroll
            for (int j = 0; j < 4; j++) {
                const float* fj = fr + j * 9;
                float f0 = fj[0], f1 = fj[1], f2 = fj[2], f3 = fj[3], f4 = fj[4],
                      f5 = fj[5], f6 = fj[6], f7 = fj[7], f8 = fj[8];
                #pragma unroll
                for (int p = 0; p < 8; p++) {
                    acc[j][p] += f0 * xv[0][p] + f1 * xv[0][p + 1] + f2 * xv[0][p + 2]
                               + f3 * xv[1][p] + f4 * xv[1][p + 1] + f5 * xv[1][p + 2]
                               + f6 * xv[2][p] + f7 * xv[2][p + 1] + f8 * xv[2][p + 2];
                }
            }
        }
    }
    // epilogue: write y + per-(b,group) partial sums
    if (tid < NG) { gsum[tid] = 0.f; gsq[tid] = 0.f; }
    __syncthreads();
    float s = 0.f, s2 = 0.f;
    const int orow = tr0 + r, oc0 = tc0 + chf;
    #pragma unroll
    for (int j = 0; j < 4; j++) {
        int co = cog * 4 + j;
        size_t base = (size_t)b * CHN * HWSZ + (size_t)co * HWSZ + (size_t)orow * WW + oc0;
        #pragma unroll
        for (int p = 0; p < 8; p++) { float a = acc[j][p]; s += a; s2 += a * a; }
        if (fp32) {
            float* yp = (float*)y + base;
            *(float4*)yp = make_float4(acc[j][0], acc[j][1], acc[j][2], acc[j][3]);
            *(float4*)(yp + 4) = make_float4(acc[j][4], acc[j][5], acc[j][6], acc[j][7]);
        } else {
            u32 w[4];
            #pragma unroll
            for (int p = 0; p < 8; p += 2)
                w[p >> 1] = (u32)f2bf(acc[j][p]) | ((u32)f2bf(acc[j][p + 1]) << 16);
            *(uint4*)((u16*)y + base) = make_uint4(w[0], w[1], w[2], w[3]);
        }
    }
    atomicAdd(&gsum[cog >> 1], s);
    atomicAdd(&gsq[cog >> 1], s2);
    __syncthreads();
    if (tid < 2 * NG) {
        int g = tid >> 1, which = tid & 1;
        float v = which ? gsq[g] : gsum[g];
        atomicAdd(&stats[(b * NG + g) * 2 + which], v);
    }
}

// ---------------- Stage 5: GroupNorm apply + LeakyReLU (in-place on y) ------
__global__ void norm_kernel(void* __restrict__ y, const float* __restrict__ stats,
                            const void* __restrict__ gamma, const void* __restrict__ beta,
                            const int* __restrict__ flag) {
    const int fp32 = *flag;
    int i8 = blockIdx.x * 256 + threadIdx.x;       // 8-element chunk index
    int idx = i8 * 8;
    int b = idx / (CHN * HWSZ);
    int co = (idx / HWSZ) & (CHN - 1);
    int g = co >> 3;
    const float invN = 1.0f / (8.0f * HWSZ);
    float sum = stats[(b * NG + g) * 2 + 0];
    float sq  = stats[(b * NG + g) * 2 + 1];
    float mean = sum * invN;
    float var = fmaxf(sq * invN - mean * mean, 0.f);
    float sc = rsqrtf(var + EPSV) * ldE(gamma, co, fp32);
    float sh = ldE(beta, co, fp32) - mean * sc;
    if (fp32) {
        float4* yp = (float4*)y + i8 * 2;
        float4 v0 = yp[0], v1 = yp[1];
        float vv[8] = {v0.x, v0.y, v0.z, v0.w, v1.x, v1.y, v1.z, v1.w};
        #pragma unroll
        for (int t = 0; t < 8; t++) {
            float a = vv[t] * sc + sh;
            vv[t] = a >= 0.f ? a : NSLOPE * a;
        }
        yp[0] = make_float4(vv[0], vv[1], vv[2], vv[3]);
        yp[1] = make_float4(vv[4], vv[5], vv[6], vv[7]);
    } else {
        uint4 v = ((uint4*)y)[i8];
        u32 w[4] = {v.x, v.y, v.z, v.w};
        #pragma unroll
        for (int t = 0; t < 4; t++) {
            float a = bf2f(w[t] & 0xffff) * sc + sh;
            float c = bf2f(w[t] >> 16) * sc + sh;
            a = a >= 0.f ? a : NSLOPE * a;
            c = c >= 0.f ? c : NSLOPE * c;
            w[t] = (u32)f2bf(a) | ((u32)f2bf(c) << 16);
        }
        ((uint4*)y)[i8] = make_uint4(w[0], w[1], w[2], w[3]);
    }
}

extern "C" void kernel_launch(void* const* d_in, const int* in_sizes, int n_in,
                              void* d_out, int out_size, void* d_ws, size_t ws_size,
                              hipStream_t stream) {
    const void* x     = d_in[0];
    const void* w1    = d_in[1];
    const void* w2    = d_in[2];
    const void* b2    = d_in[3];
    const void* wts   = d_in[4];
    const void* gamma = d_in[5];
    const void* beta  = d_in[6];
    float* ws = (float*)d_ws;
    int*   flag    = (int*)ws;              // [0]
    float* pooled  = ws + 16;               // 1024 floats
    float* attn    = ws + 16 + 1024;        // 64 floats
    float* stats   = ws + 16 + 1024 + 64;   // 256 floats (sum,sumsq per b,g)

    detect_kernel<<<1, 256, 0, stream>>>((const u16*)x, flag);
    pool_kernel<<<BN * CHN, 256, 0, stream>>>(x, pooled, flag);
    attn_kernel<<<1, 64, 0, stream>>>(pooled, w1, w2, b2, attn, stats, flag);
    dim3 cg(WW / 16, HH / 8, BN);
    conv_kernel<<<cg, 256, 0, stream>>>(x, wts, attn, d_out, stats, flag);
    norm_kernel<<<(BN * CHN * HWSZ) / 8 / 256, 256, 0, stream>>>(d_out, stats, gamma, beta, flag);
}

// Round 3
// 538.893 us; speedup vs baseline: 2.1113x; 2.1113x over previous
//
#include <hip/hip_runtime.h>

typedef unsigned short u16;
typedef unsigned int u32;
typedef _Float16 f16;
typedef __attribute__((ext_vector_type(8))) f16 v8h;
typedef __attribute__((ext_vector_type(4))) f16 v4h;
typedef __attribute__((ext_vector_type(16))) float v16f;

#define BN 16
#define CHN 64
#define HH 192
#define WW 192
#define HWSZ 36864
#define KDY 4
#define HIDN 17
#define NG 8
#define TEMP_ 30.0f
#define EPSV 1e-5f
#define NSLOPE 0.01f

// conv tiling: 8 rows x 32 cols output tile per workgroup, halo 10x34
#define TR 8
#define TC 32
#define HR 10
#define HC 34
#define PSTR 34          // u32 stride per halo pixel: 32 ci-pairs + 2 pad (bank step 2 -> free)

__device__ float g_pooled[BN * CHN];
__device__ float g_attn[BN * KDY];
__device__ float g_stats[BN * NG * 2];
__device__ __align__(16) f16 g_filt[BN * 9 * CHN * CHN];   // [b][tap][co][ci], 1.18 MB

// ---------------- Stage 1: global average pool (fp32 in) ----------------
__global__ void pool_kernel(const float* __restrict__ x) {
    int bc = blockIdx.x;
    const float4* pv = (const float4*)(x + (size_t)bc * HWSZ);
    float s = 0.f;
    for (int i = threadIdx.x; i < HWSZ / 4; i += 256) {
        float4 v = pv[i];
        s += v.x + v.y + v.z + v.w;
    }
    #pragma unroll
    for (int off = 32; off > 0; off >>= 1) s += __shfl_down(s, off);
    __shared__ float ls[4];
    if ((threadIdx.x & 63) == 0) ls[threadIdx.x >> 6] = s;
    __syncthreads();
    if (threadIdx.x == 0)
        g_pooled[bc] = (ls[0] + ls[1] + ls[2] + ls[3]) * (1.0f / HWSZ);
}

// ---------------- Stage 2: attention MLP + softmax; zeroes GN stats ---------
__global__ void attn_kernel(const float* __restrict__ w1, const float* __restrict__ w2,
                            const float* __restrict__ b2) {
    int t = threadIdx.x;
    for (int i = t; i < BN * NG * 2; i += 64) g_stats[i] = 0.f;
    if (t < BN) {
        const float* pr = g_pooled + t * CHN;
        float hb[HIDN];
        #pragma unroll
        for (int h = 0; h < HIDN; h++) {
            float s = 0.f;
            for (int c = 0; c < CHN; c++) s += w1[h * CHN + c] * pr[c];
            hb[h] = fmaxf(s, 0.f);
        }
        float scv[KDY]; float m = -3e38f;
        #pragma unroll
        for (int k = 0; k < KDY; k++) {
            float s = b2[k];
            for (int h = 0; h < HIDN; h++) s += w2[k * HIDN + h] * hb[h];
            s *= (1.0f / TEMP_);
            scv[k] = s; m = fmaxf(m, s);
        }
        float den = 0.f;
        #pragma unroll
        for (int k = 0; k < KDY; k++) { scv[k] = __expf(scv[k] - m); den += scv[k]; }
        float rd = 1.f / den;
        #pragma unroll
        for (int k = 0; k < KDY; k++) g_attn[t * KDY + k] = scv[k] * rd;
    }
}

// ---------------- Stage 3: synthesize fp16 filters [b][tap][co][ci] ---------
// grid = 9*64*64/256 = 144 blocks; each thread does one (tap,co,ci), all 16 b.
__global__ void filt_kernel(const float* __restrict__ wts) {
    __shared__ float at[BN * KDY];
    if (threadIdx.x < BN * KDY) at[threadIdx.x] = g_attn[threadIdx.x];
    __syncthreads();
    int t = blockIdx.x * 256 + threadIdx.x;     // < 36864
    int tap = t / 4096;
    int co = (t >> 6) & 63;
    int ci = t & 63;
    float w0 = wts[((0 * CHN + co) * CHN + ci) * 9 + tap];
    float w1 = wts[((1 * CHN + co) * CHN + ci) * 9 + tap];
    float w2 = wts[((2 * CHN + co) * CHN + ci) * 9 + tap];
    float w3 = wts[((3 * CHN + co) * CHN + ci) * 9 + tap];
    #pragma unroll
    for (int b = 0; b < BN; b++) {
        float v = at[b * 4] * w0 + at[b * 4 + 1] * w1
                + at[b * 4 + 2] * w2 + at[b * 4 + 3] * w3;
        g_filt[((b * 9 + tap) * CHN + co) * CHN + ci] = (f16)v;
    }
}

// ---------------- Stage 4: MFMA implicit-GEMM conv + fused GN stats ---------
// block = 256 (4 waves). wave w owns output rows {2w, 2w+1} (pxblk j), cols = lane&31.
// Each wave: 2 co-bands x 2 rows => 4 v16f accumulators.
// K-loop: 9 taps x 4 ci-blocks of 16, MFMA 32x32x16 f16.
// A-frag: A[m=lane&31][k=8*(lane>>5)+i] from g_filt (global, L2-hot).
// B-frag: B[n=lane&31][k=8*(lane>>5)+i] from LDS x-tile (pixel-major, ci contig).
// C/D: col(n)=lane&31, row(co)=(r&3)+8*(r>>2)+4*(lane>>5)  [m74/m101]
__global__ void __launch_bounds__(256) conv_kernel(const float* __restrict__ x,
                                                   float* __restrict__ y) {
    __shared__ __align__(16) u32 xs[HR * HC * PSTR];   // 46240 B
    __shared__ float gsum[NG], gsq[NG];
    const int b = blockIdx.z;
    const int r0 = blockIdx.y * TR, c0 = blockIdx.x * TC;
    const int tid = threadIdx.x;
    const int w = tid >> 6, lane = tid & 63;
    const int n = lane & 31, hi = lane >> 5;
    if (tid < NG) { gsum[tid] = 0.f; gsq[tid] = 0.f; }

    // stage x halo tile, transposed to [pixel][ci] fp16 pairs
    const float* xb = x + (size_t)b * CHN * HWSZ;
    for (int l = tid; l < HR * HC * 32; l += 256) {
        int cp = l / (HR * HC);                 // ci pair 0..31
        int pix = l - cp * (HR * HC);           // 0..339 (hc fastest -> coalesced)
        int hr = pix / HC, hc = pix - hr * HC;
        int gr = r0 - 1 + hr, gc = c0 - 1 + hc;
        float v0 = 0.f, v1 = 0.f;
        if ((unsigned)gr < HH && (unsigned)gc < WW) {
            const float* p = xb + (size_t)(2 * cp) * HWSZ + gr * WW + gc;
            v0 = p[0]; v1 = p[HWSZ];
        }
        u32 pk = (u32)__builtin_bit_cast(u16, (f16)v0)
               | ((u32)__builtin_bit_cast(u16, (f16)v1) << 16);
        xs[pix * PSTR + cp] = pk;
    }
    __syncthreads();

    const f16* xsh = (const f16*)xs;
    const f16* fb = g_filt + (size_t)b * 9 * CHN * CHN + (size_t)n * CHN + hi * 8;
    v16f acc00 = {}, acc01 = {}, acc10 = {}, acc11 = {};

    v8h a0c = *(const v8h*)fb;                 // it=0: tap0, kblk0
    v8h a1c = *(const v8h*)(fb + 32 * CHN);
    for (int it = 0; it < 36; it++) {
        int tap = it >> 2, kblk = it & 3;
        v8h a0n = a0c, a1n = a1c;
        if (it < 35) {                          // prefetch next A frags
            int t2 = it + 1;
            const f16* p = fb + (t2 >> 2) * (CHN * CHN) + (t2 & 3) * 16;
            a0n = *(const v8h*)p;
            a1n = *(const v8h*)(p + 32 * CHN);
        }
        int dy = tap / 3, dx = tap - 3 * dy;
        // halo pixel of output row (2w+j)+dy, col n+dx; half index = pix*68 + ci0
        int hb = ((2 * w + dy) * HC + (n + dx)) * (PSTR * 2) + kblk * 16 + hi * 8;
        v4h lo0 = *(const v4h*)(xsh + hb);
        v4h up0 = *(const v4h*)(xsh + hb + 4);
        v4h lo1 = *(const v4h*)(xsh + hb + HC * PSTR * 2);
        v4h up1 = *(const v4h*)(xsh + hb + HC * PSTR * 2 + 4);
        v8h b0 = __builtin_shufflevector(lo0, up0, 0, 1, 2, 3, 4, 5, 6, 7);
        v8h b1 = __builtin_shufflevector(lo1, up1, 0, 1, 2, 3, 4, 5, 6, 7);
        acc00 = __builtin_amdgcn_mfma_f32_32x32x16_f16(a0c, b0, acc00, 0, 0, 0);
        acc01 = __builtin_amdgcn_mfma_f32_32x32x16_f16(a0c, b1, acc01, 0, 0, 0);
        acc10 = __builtin_amdgcn_mfma_f32_32x32x16_f16(a1c, b0, acc10, 0, 0, 0);
        acc11 = __builtin_amdgcn_mfma_f32_32x32x16_f16(a1c, b1, acc11, 0, 0, 0);
        a0c = a0n; a1c = a1n;
    }

    // epilogue: scatter to y (fp32) + fused GN partial stats
    float sg[NG], sq[NG];
    #pragma unroll
    for (int g = 0; g < NG; g++) { sg[g] = 0.f; sq[g] = 0.f; }
    float* yb = y + (size_t)b * CHN * HWSZ + (size_t)(r0 + 2 * w) * WW + (c0 + n);
#define EPI(ACC, CH, J) { v16f a = ACC; \
    _Pragma("unroll") \
    for (int r = 0; r < 16; r++) { \
        int co = CH * 32 + (r & 3) + 8 * (r >> 2) + 4 * hi; \
        yb[(size_t)co * HWSZ + J * WW] = a[r]; \
        int g = (r >> 2) + 4 * CH; \
        sg[g] += a[r]; sq[g] += a[r] * a[r]; } }
    EPI(acc00, 0, 0) EPI(acc01, 0, 1) EPI(acc10, 1, 0) EPI(acc11, 1, 1)
#undef EPI
    #pragma unroll
    for (int g = 0; g < NG; g++) {
        float s = sg[g], q = sq[g];
        #pragma unroll
        for (int off = 32; off > 0; off >>= 1) {
            s += __shfl_down(s, off);
            q += __shfl_down(q, off);
        }
        if (lane == 0) { atomicAdd(&gsum[g], s); atomicAdd(&gsq[g], q); }
    }
    __syncthreads();
    if (tid < 2 * NG) {
        int g = tid >> 1, which = tid & 1;
        atomicAdd(&g_stats[(b * NG + g) * 2 + which], which ? gsq[g] : gsum[g]);
    }
}

// ---------------- Stage 5: GroupNorm apply + LeakyReLU (in-place, fp32) -----
__global__ void norm_kernel(float* __restrict__ y, const float* __restrict__ gamma,
                            const float* __restrict__ beta) {
    int i8 = blockIdx.x * 256 + threadIdx.x;       // 8-float chunk index
    int idx = i8 * 8;
    int b = idx / (CHN * HWSZ);
    int co = (idx / HWSZ) & (CHN - 1);
    int g = co >> 3;
    const float invN = 1.0f / (8.0f * HWSZ);
    float mean = g_stats[(b * NG + g) * 2 + 0] * invN;
    float var = fmaxf(g_stats[(b * NG + g) * 2 + 1] * invN - mean * mean, 0.f);
    float sc = rsqrtf(var + EPSV) * gamma[co];
    float sh = beta[co] - mean * sc;
    float4* yp = (float4*)y + i8 * 2;
    float4 v0 = yp[0], v1 = yp[1];
    float vv[8] = {v0.x, v0.y, v0.z, v0.w, v1.x, v1.y, v1.z, v1.w};
    #pragma unroll
    for (int t = 0; t < 8; t++) {
        float a = vv[t] * sc + sh;
        vv[t] = a >= 0.f ? a : NSLOPE * a;
    }
    yp[0] = make_float4(vv[0], vv[1], vv[2], vv[3]);
    yp[1] = make_float4(vv[4], vv[5], vv[6], vv[7]);
}

extern "C" void kernel_launch(void* const* d_in, const int* in_sizes, int n_in,
                              void* d_out, int out_size, void* d_ws, size_t ws_size,
                              hipStream_t stream) {
    const float* x     = (const float*)d_in[0];
    const float* w1    = (const float*)d_in[1];
    const float* w2    = (const float*)d_in[2];
    const float* b2    = (const float*)d_in[3];
    const float* wts   = (const float*)d_in[4];
    const float* gamma = (const float*)d_in[5];
    const float* beta  = (const float*)d_in[6];
    float* out = (float*)d_out;

    pool_kernel<<<BN * CHN, 256, 0, stream>>>(x);
    attn_kernel<<<1, 64, 0, stream>>>(w1, w2, b2);
    filt_kernel<<<144, 256, 0, stream>>>(wts);
    dim3 cg(WW / TC, HH / TR, BN);
    conv_kernel<<<cg, 256, 0, stream>>>(x, out);
    norm_kernel<<<BN * CHN * HWSZ / 8 / 256, 256, 0, stream>>>(out, gamma, beta);
}